// Round 1
// baseline (329.510 us; speedup 1.0000x reference)
//
#include <hip/hip_runtime.h>
#include <math.h>

// Problem constants
#define NB 16
#define NF 5
#define NV 4
#define NIMG (NB*NF*NV)          // 320 images
#define IMG_HW 224
#define IMG_CH_STRIDE (224*224)  // 50176
#define H1_HW 37                 // after conv1(s2)+pool3: 111 -> 37
#define H1_CH_STRIDE (37*37)     // 1369

// ---------------------------------------------------------------------------
// Kernel 1: conv1 (3->3, k=3, s=2, VALID) + maxpool(3,3) + ReLU, fused.
// One thread per (image, pooled_y, pooled_x); computes all 3 out-channels.
// Pooled output (py,px) depends on input rows 6py..6py+6, cols 6px..6px+6.
// ---------------------------------------------------------------------------
__global__ __launch_bounds__(256) void k1_conv1_pool(
    const float* __restrict__ nodes,   // [320,3,224,224]
    const float* __restrict__ w,       // [3,3,3,3] OIHW
    const float* __restrict__ bias,    // [3]
    float* __restrict__ h1)            // [320,3,37,37]
{
    int tid = blockIdx.x * 256 + threadIdx.x;
    const int TOT = NIMG * H1_HW * H1_HW;   // 438080
    if (tid >= TOT) return;
    int b   = tid / (H1_HW * H1_HW);
    int rem = tid - b * (H1_HW * H1_HW);
    int py  = rem / H1_HW;
    int px  = rem - py * H1_HW;

    const float* inb = nodes + (size_t)b * 3 * IMG_CH_STRIDE;
    const int r0 = 6 * py, c0 = 6 * px;

    // acc[oc][conv_pos], conv_pos = i*3+j over the 3x3 pooled window
    float acc[3][9];
    #pragma unroll
    for (int oc = 0; oc < 3; ++oc)
        #pragma unroll
        for (int p = 0; p < 9; ++p) acc[oc][p] = 0.f;

    #pragma unroll
    for (int ic = 0; ic < 3; ++ic) {
        // Load the 7x7 input patch for this channel
        float patch[7][7];
        const float* ip = inb + ic * IMG_CH_STRIDE + r0 * IMG_HW + c0;
        #pragma unroll
        for (int r = 0; r < 7; ++r)
            #pragma unroll
            for (int c = 0; c < 7; ++c)
                patch[r][c] = ip[r * IMG_HW + c];

        // Weights for this input channel: w[oc][ic][ky][kx]
        float wv[3][3][3];
        #pragma unroll
        for (int oc = 0; oc < 3; ++oc)
            #pragma unroll
            for (int ky = 0; ky < 3; ++ky)
                #pragma unroll
                for (int kx = 0; kx < 3; ++kx)
                    wv[oc][ky][kx] = w[((oc * 3 + ic) * 3 + ky) * 3 + kx];

        #pragma unroll
        for (int i = 0; i < 3; ++i)
            #pragma unroll
            for (int j = 0; j < 3; ++j) {
                const int p = i * 3 + j;
                #pragma unroll
                for (int ky = 0; ky < 3; ++ky)
                    #pragma unroll
                    for (int kx = 0; kx < 3; ++kx) {
                        float x = patch[2 * i + ky][2 * j + kx];
                        acc[0][p] += wv[0][ky][kx] * x;
                        acc[1][p] += wv[1][ky][kx] * x;
                        acc[2][p] += wv[2][ky][kx] * x;
                    }
            }
    }

    float* outb = h1 + (size_t)b * 3 * H1_CH_STRIDE + py * H1_HW + px;
    #pragma unroll
    for (int oc = 0; oc < 3; ++oc) {
        float m = -INFINITY;
        #pragma unroll
        for (int p = 0; p < 9; ++p) m = fmaxf(m, acc[oc][p]);
        m += bias[oc];            // max(a_p) + b == max(a_p + b)
        m = fmaxf(m, 0.f);        // relu(maxpool(conv))
        outb[oc * H1_CH_STRIDE] = m;
    }
}

// ---------------------------------------------------------------------------
// Kernel 2: conv2 (3->1, k=3, s=2) + maxpool(3,3) + ReLU + linear 36->6.
// One block (64 threads) per image.
// ---------------------------------------------------------------------------
__global__ __launch_bounds__(64) void k2_conv2_pool_lin(
    const float* __restrict__ h1,     // [320,3,37,37]
    const float* __restrict__ w2,     // [1,3,3,3]
    const float* __restrict__ b2,     // [1]
    const float* __restrict__ lin_w,  // [36,6]
    const float* __restrict__ lin_b,  // [6]
    float* __restrict__ feat)         // [320,6]
{
    int b = blockIdx.x;
    int t = threadIdx.x;
    __shared__ float s_h2[36];

    if (t < 36) {
        int py = t / 6, px = t - (t / 6) * 6;
        const float* hb = h1 + (size_t)b * 3 * H1_CH_STRIDE;
        float m = -INFINITY;
        #pragma unroll
        for (int i = 0; i < 3; ++i)
            #pragma unroll
            for (int j = 0; j < 3; ++j) {
                int oy = 3 * py + i, ox = 3 * px + j;
                float a = 0.f;
                #pragma unroll
                for (int ic = 0; ic < 3; ++ic)
                    #pragma unroll
                    for (int ky = 0; ky < 3; ++ky)
                        #pragma unroll
                        for (int kx = 0; kx < 3; ++kx)
                            a += w2[(ic * 3 + ky) * 3 + kx] *
                                 hb[ic * H1_CH_STRIDE + (2 * oy + ky) * H1_HW + (2 * ox + kx)];
                m = fmaxf(m, a);
            }
        m += b2[0];
        s_h2[t] = fmaxf(m, 0.f);
    }
    __syncthreads();
    if (t < 6) {
        float a = lin_b[t];
        #pragma unroll
        for (int i = 0; i < 36; ++i) a += s_h2[i] * lin_w[i * 6 + t];
        feat[b * 6 + t] = a;
    }
}

// ---------------------------------------------------------------------------
// Kernel 3: edge weights + attention aggregation + last-frame message +
// readout MLP. One block (128 threads) per batch element.
// ---------------------------------------------------------------------------
__global__ __launch_bounds__(128) void k3_graph_mlp(
    const float* __restrict__ feat,    // [320,6] = [NB,NF,NV,6]
    const float* __restrict__ pos,     // [NB,NF,NV,6]
    const float* __restrict__ attmap,  // [NB,NF,NV,NV]
    const float* __restrict__ wfc_w,   // [24]
    const float* __restrict__ wfc_b,   // [1]
    const float* __restrict__ fm_w,    // [6,6]
    const float* __restrict__ fm_b,    // [6]
    const float* __restrict__ lm_w,    // [6,6]
    const float* __restrict__ lm_b,    // [6]
    const float* __restrict__ fc1_w,   // [240,120]
    const float* __restrict__ fc1_b,   // [120]
    const float* __restrict__ fc2_w,   // [120,60]
    const float* __restrict__ fc2_b,   // [60]
    const float* __restrict__ fc3_w,   // [60,6]
    const float* __restrict__ fc3_b,   // [6]
    float* __restrict__ out)           // [NB,6]
{
    int b = blockIdx.x;
    int t = threadIdx.x;

    __shared__ float s_na[NF][NV][12];   // feat || pos
    __shared__ float s_pm[NF][NV][6];
    __shared__ float s_maw[NF][NV][NV];  // [f][s][t]
    __shared__ float s_inp[240];
    __shared__ float s_r1[120];
    __shared__ float s_r2[60];

    // Phase A: load feat+pos into s_na; feat part also into s_inp
    if (t < 120) {
        int f = t / 24;
        int v = (t / 6) % 4;
        int d = t % 6;
        float fv = feat[((b * NF + f) * NV + v) * 6 + d];
        float pv = pos[((b * NF + f) * NV + v) * 6 + d];
        s_na[f][v][d]     = fv;
        s_na[f][v][6 + d] = pv;
        s_inp[(f * NV + v) * 12 + d] = fv;
    }
    __syncthreads();

    // Phase B: pm[f][v][d] and maw[f][s][t]
    if (t < 120) {
        int f = t / 24;
        int v = (t / 6) % 4;
        int d = t % 6;
        float a = fm_b[d];
        #pragma unroll
        for (int k = 0; k < 6; ++k) a += s_na[f][v][6 + k] * fm_w[k * 6 + d];
        s_pm[f][v][d] = a;
    }
    if (t < 80) {
        int f = t / 16;
        int s = (t / 4) % 4;
        int tt = t % 4;
        float x = wfc_b[0];
        #pragma unroll
        for (int k = 0; k < 12; ++k)
            x += wfc_w[k] * s_na[f][s][k] + wfc_w[12 + k] * s_na[f][tt][k];
        float sig = 1.f / (1.f + expf(-x));
        s_maw[f][s][tt] = sig + attmap[((b * NF + f) * NV + s) * NV + tt];
    }
    __syncthreads();

    // Phase C: pos_up[f][n][d] = sum_s maw[f][s][n]*pm[f][s][d] (+ lm for f>0)
    if (t < 120) {
        int f = t / 24;
        int n = (t / 6) % 4;
        int d = t % 6;
        float a = 0.f;
        #pragma unroll
        for (int s = 0; s < 4; ++s) a += s_maw[f][s][n] * s_pm[f][s][d];
        if (f > 0) {
            float l = lm_b[d];
            #pragma unroll
            for (int k = 0; k < 6; ++k) l += s_na[f - 1][n][6 + k] * lm_w[k * 6 + d];
            a += l;
        }
        s_inp[(f * NV + n) * 12 + 6 + d] = a;
    }
    __syncthreads();

    // Phase D: fc1 (240 -> 120) + relu
    if (t < 120) {
        float a = fc1_b[t];
        for (int i = 0; i < 240; ++i) a += s_inp[i] * fc1_w[i * 120 + t];
        s_r1[t] = fmaxf(a, 0.f);
    }
    __syncthreads();

    // Phase E: fc2 (120 -> 60) + relu
    if (t < 60) {
        float a = fc2_b[t];
        for (int i = 0; i < 120; ++i) a += s_r1[i] * fc2_w[i * 60 + t];
        s_r2[t] = fmaxf(a, 0.f);
    }
    __syncthreads();

    // Phase F: fc3 (60 -> 6)
    if (t < 6) {
        float a = fc3_b[t];
        for (int i = 0; i < 60; ++i) a += s_r2[i] * fc3_w[i * 6 + t];
        out[b * 6 + t] = a;
    }
}

// ---------------------------------------------------------------------------
extern "C" void kernel_launch(void* const* d_in, const int* in_sizes, int n_in,
                              void* d_out, int out_size, void* d_ws, size_t ws_size,
                              hipStream_t stream) {
    const float* nodes   = (const float*)d_in[0];
    const float* pos     = (const float*)d_in[1];
    const float* attmap  = (const float*)d_in[2];
    // d_in[3] = depths : unused by the reference
    const float* conv1_w = (const float*)d_in[4];
    const float* conv1_b = (const float*)d_in[5];
    const float* conv2_w = (const float*)d_in[6];
    const float* conv2_b = (const float*)d_in[7];
    const float* lin_w   = (const float*)d_in[8];
    const float* lin_b   = (const float*)d_in[9];
    const float* wfc_w   = (const float*)d_in[10];
    const float* wfc_b   = (const float*)d_in[11];
    const float* fm_w    = (const float*)d_in[12];
    const float* fm_b    = (const float*)d_in[13];
    const float* lm_w    = (const float*)d_in[14];
    const float* lm_b    = (const float*)d_in[15];
    const float* fc1_w   = (const float*)d_in[16];
    const float* fc1_b   = (const float*)d_in[17];
    const float* fc2_w   = (const float*)d_in[18];
    const float* fc2_b   = (const float*)d_in[19];
    const float* fc3_w   = (const float*)d_in[20];
    const float* fc3_b   = (const float*)d_in[21];

    float* h1      = (float*)d_ws;                        // 320*3*37*37 = 1,314,240 floats
    float* feat_ws = h1 + (size_t)NIMG * 3 * H1_CH_STRIDE; // 320*6 floats

    const int tot1 = NIMG * H1_HW * H1_HW;                // 438080
    k1_conv1_pool<<<(tot1 + 255) / 256, 256, 0, stream>>>(nodes, conv1_w, conv1_b, h1);
    k2_conv2_pool_lin<<<NIMG, 64, 0, stream>>>(h1, conv2_w, conv2_b, lin_w, lin_b, feat_ws);
    k3_graph_mlp<<<NB, 128, 0, stream>>>(feat_ws, pos, attmap,
                                         wfc_w, wfc_b, fm_w, fm_b, lm_w, lm_b,
                                         fc1_w, fc1_b, fc2_w, fc2_b, fc3_w, fc3_b,
                                         (float*)d_out);
}

// Round 2
// 327.993 us; speedup vs baseline: 1.0046x; 1.0046x over previous
//
#include <hip/hip_runtime.h>
#include <math.h>

// Problem constants
#define NB 16
#define NF 5
#define NV 4
#define NIMG (NB*NF*NV)          // 320 images
#define IMG_HW 224
#define IMG_CH_STRIDE (224*224)  // 50176
#define H1_HW 37                 // after conv1(s2)+pool3: 111 -> 37
#define H1_CH_STRIDE (37*37)     // 1369
#define H1_IMG 4108              // 3*1369 = 4107, padded to multiple of 4 floats (16B)

// ---------------------------------------------------------------------------
// Kernel 1: conv1 (3->3, k=3, s=2, VALID) + maxpool(3,3) + ReLU, fused.
// One block per (image, pooled_row). Stage the 3ch x 7row x 224col input band
// into LDS via coalesced float4 (each channel-band is contiguous, 16B aligned),
// then 37 threads compute all 3 out-channels for their pooled column from LDS.
// ---------------------------------------------------------------------------
__global__ __launch_bounds__(256) void k1_conv1_pool(
    const float* __restrict__ nodes,   // [320,3,224,224]
    const float* __restrict__ w,       // [3,3,3,3] OIHW
    const float* __restrict__ bias,    // [3]
    float* __restrict__ h1)            // [320, H1_IMG] padded; [3,37,37] inside
{
    const int blk = blockIdx.x;          // img*37 + py
    const int img = blk / H1_HW;
    const int py  = blk - img * H1_HW;
    const int t   = threadIdx.x;

    __shared__ float s[3 * 7 * 224];     // 4704 floats = 18816 B

    const float* src = nodes + (size_t)img * 3 * IMG_CH_STRIDE + py * 6 * IMG_HW;

    // Stage: 3 chunks of 1568 floats (392 float4 each), fully coalesced.
    {
        const float4* s0 = (const float4*)(src);
        const float4* s1 = (const float4*)(src + IMG_CH_STRIDE);
        const float4* s2 = (const float4*)(src + 2 * IMG_CH_STRIDE);
        float4* d0 = (float4*)s;
        float4* d1 = (float4*)(s + 1568);
        float4* d2 = (float4*)(s + 3136);
        const bool hi = (t < 392 - 256);   // t < 136 does the second pass
        float4 a0 = s0[t], a1 = s1[t], a2 = s2[t];
        float4 b0, b1, b2;
        if (hi) { b0 = s0[t + 256]; b1 = s1[t + 256]; b2 = s2[t + 256]; }
        d0[t] = a0; d1[t] = a1; d2[t] = a2;
        if (hi) { d0[t + 256] = b0; d1[t + 256] = b1; d2[t + 256] = b2; }
    }
    __syncthreads();

    if (t < H1_HW) {
        const int px = t;
        float acc[3][9];
        #pragma unroll
        for (int oc = 0; oc < 3; ++oc)
            #pragma unroll
            for (int p = 0; p < 9; ++p) acc[oc][p] = 0.f;

        #pragma unroll
        for (int ic = 0; ic < 3; ++ic) {
            // weights for this input channel (uniform -> scalar cached)
            float wv[3][3][3];
            #pragma unroll
            for (int oc = 0; oc < 3; ++oc)
                #pragma unroll
                for (int ky = 0; ky < 3; ++ky)
                    #pragma unroll
                    for (int kx = 0; kx < 3; ++kx)
                        wv[oc][ky][kx] = w[((oc * 3 + ic) * 3 + ky) * 3 + kx];

            // 7x7 patch from LDS via aligned float2 (6*px is even -> 8B aligned).
            // Loads cols 6px..6px+7 (6px+7 <= 223 for px<=36: in-bounds).
            float patch[7][8];
            #pragma unroll
            for (int r = 0; r < 7; ++r) {
                const float* row = s + ic * 1568 + r * 224 + 6 * px;
                #pragma unroll
                for (int k = 0; k < 4; ++k) {
                    float2 q = *(const float2*)(row + 2 * k);
                    patch[r][2 * k]     = q.x;
                    patch[r][2 * k + 1] = q.y;
                }
            }

            #pragma unroll
            for (int i = 0; i < 3; ++i)
                #pragma unroll
                for (int j = 0; j < 3; ++j) {
                    const int p = i * 3 + j;
                    #pragma unroll
                    for (int ky = 0; ky < 3; ++ky)
                        #pragma unroll
                        for (int kx = 0; kx < 3; ++kx) {
                            float x = patch[2 * i + ky][2 * j + kx];
                            acc[0][p] += wv[0][ky][kx] * x;
                            acc[1][p] += wv[1][ky][kx] * x;
                            acc[2][p] += wv[2][ky][kx] * x;
                        }
                }
        }

        float* outb = h1 + (size_t)img * H1_IMG + py * H1_HW + px;
        #pragma unroll
        for (int oc = 0; oc < 3; ++oc) {
            float m = -INFINITY;
            #pragma unroll
            for (int p = 0; p < 9; ++p) m = fmaxf(m, acc[oc][p]);
            m += bias[oc];           // max(a)+b == max(a+b)
            m = fmaxf(m, 0.f);
            outb[oc * H1_CH_STRIDE] = m;
        }
    }
}

// ---------------------------------------------------------------------------
// Kernel 2: conv2 (3->1, k=3, s=2) + maxpool(3,3) + ReLU + linear 36->6.
// One block (128 threads) per image; h1 image staged to LDS via float4.
// ---------------------------------------------------------------------------
__global__ __launch_bounds__(128) void k2_conv2_pool_lin(
    const float* __restrict__ h1,     // [320, H1_IMG]
    const float* __restrict__ w2,     // [1,3,3,3]
    const float* __restrict__ b2,     // [1]
    const float* __restrict__ lin_w,  // [36,6]
    const float* __restrict__ lin_b,  // [6]
    float* __restrict__ feat)         // [320,6]
{
    const int img = blockIdx.x;
    const int t   = threadIdx.x;
    __shared__ float s[H1_IMG];       // 4108 floats (last one is pad, unused)
    __shared__ float s_h2[36];

    // Stage 1027 float4 (= 4108 floats) with 128 threads: 8 full + 1 partial.
    {
        const float4* src = (const float4*)(h1 + (size_t)img * H1_IMG);
        float4* d = (float4*)s;
        float4 v[8];
        #pragma unroll
        for (int k = 0; k < 8; ++k) v[k] = src[t + 128 * k];   // max 127+896=1023 < 1027
        const bool hi = (t < 1027 - 1024);                      // t < 3
        float4 v8;
        if (hi) v8 = src[t + 1024];
        #pragma unroll
        for (int k = 0; k < 8; ++k) d[t + 128 * k] = v[k];
        if (hi) d[t + 1024] = v8;
    }
    __syncthreads();

    if (t < 36) {
        const int py = t / 6, px = t - (t / 6) * 6;
        float m = -INFINITY;
        #pragma unroll
        for (int i = 0; i < 3; ++i)
            #pragma unroll
            for (int j = 0; j < 3; ++j) {
                const int oy = 3 * py + i, ox = 3 * px + j;
                float a = 0.f;
                #pragma unroll
                for (int ic = 0; ic < 3; ++ic)
                    #pragma unroll
                    for (int ky = 0; ky < 3; ++ky)
                        #pragma unroll
                        for (int kx = 0; kx < 3; ++kx)
                            a += w2[(ic * 3 + ky) * 3 + kx] *
                                 s[ic * H1_CH_STRIDE + (2 * oy + ky) * H1_HW + (2 * ox + kx)];
                m = fmaxf(m, a);
            }
        m += b2[0];
        s_h2[t] = fmaxf(m, 0.f);
    }
    __syncthreads();
    if (t < 6) {
        float a = lin_b[t];
        #pragma unroll
        for (int i = 0; i < 36; ++i) a += s_h2[i] * lin_w[i * 6 + t];
        feat[img * 6 + t] = a;
    }
}

// ---------------------------------------------------------------------------
// Kernel 3: edge weights + attention aggregation + last-frame message +
// readout MLP. One block (128 threads) per batch element.
// ---------------------------------------------------------------------------
__global__ __launch_bounds__(128) void k3_graph_mlp(
    const float* __restrict__ feat,    // [320,6] = [NB,NF,NV,6]
    const float* __restrict__ pos,     // [NB,NF,NV,6]
    const float* __restrict__ attmap,  // [NB,NF,NV,NV]
    const float* __restrict__ wfc_w,   // [24]
    const float* __restrict__ wfc_b,   // [1]
    const float* __restrict__ fm_w,    // [6,6]
    const float* __restrict__ fm_b,    // [6]
    const float* __restrict__ lm_w,    // [6,6]
    const float* __restrict__ lm_b,    // [6]
    const float* __restrict__ fc1_w,   // [240,120]
    const float* __restrict__ fc1_b,   // [120]
    const float* __restrict__ fc2_w,   // [120,60]
    const float* __restrict__ fc2_b,   // [60]
    const float* __restrict__ fc3_w,   // [60,6]
    const float* __restrict__ fc3_b,   // [6]
    float* __restrict__ out)           // [NB,6]
{
    const int b = blockIdx.x;
    const int t = threadIdx.x;

    __shared__ float s_na[NF][NV][12];   // feat || pos
    __shared__ float s_pm[NF][NV][6];
    __shared__ float s_maw[NF][NV][NV];  // [f][s][t]
    __shared__ float s_inp[240];
    __shared__ float s_r1[120];
    __shared__ float s_r2[60];

    if (t < 120) {
        int f = t / 24;
        int v = (t / 6) % 4;
        int d = t % 6;
        float fv = feat[((b * NF + f) * NV + v) * 6 + d];
        float pv = pos[((b * NF + f) * NV + v) * 6 + d];
        s_na[f][v][d]     = fv;
        s_na[f][v][6 + d] = pv;
        s_inp[(f * NV + v) * 12 + d] = fv;
    }
    __syncthreads();

    if (t < 120) {
        int f = t / 24;
        int v = (t / 6) % 4;
        int d = t % 6;
        float a = fm_b[d];
        #pragma unroll
        for (int k = 0; k < 6; ++k) a += s_na[f][v][6 + k] * fm_w[k * 6 + d];
        s_pm[f][v][d] = a;
    }
    if (t < 80) {
        int f = t / 16;
        int sidx = (t / 4) % 4;
        int tt = t % 4;
        float x = wfc_b[0];
        #pragma unroll
        for (int k = 0; k < 12; ++k)
            x += wfc_w[k] * s_na[f][sidx][k] + wfc_w[12 + k] * s_na[f][tt][k];
        float sig = 1.f / (1.f + expf(-x));
        s_maw[f][sidx][tt] = sig + attmap[((b * NF + f) * NV + sidx) * NV + tt];
    }
    __syncthreads();

    if (t < 120) {
        int f = t / 24;
        int n = (t / 6) % 4;
        int d = t % 6;
        float a = 0.f;
        #pragma unroll
        for (int sidx = 0; sidx < 4; ++sidx) a += s_maw[f][sidx][n] * s_pm[f][sidx][d];
        if (f > 0) {
            float l = lm_b[d];
            #pragma unroll
            for (int k = 0; k < 6; ++k) l += s_na[f - 1][n][6 + k] * lm_w[k * 6 + d];
            a += l;
        }
        s_inp[(f * NV + n) * 12 + 6 + d] = a;
    }
    __syncthreads();

    if (t < 120) {
        float a = fc1_b[t];
        #pragma unroll 16
        for (int i = 0; i < 240; ++i) a += s_inp[i] * fc1_w[i * 120 + t];
        s_r1[t] = fmaxf(a, 0.f);
    }
    __syncthreads();

    if (t < 60) {
        float a = fc2_b[t];
        #pragma unroll 16
        for (int i = 0; i < 120; ++i) a += s_r1[i] * fc2_w[i * 60 + t];
        s_r2[t] = fmaxf(a, 0.f);
    }
    __syncthreads();

    if (t < 6) {
        float a = fc3_b[t];
        #pragma unroll 12
        for (int i = 0; i < 60; ++i) a += s_r2[i] * fc3_w[i * 6 + t];
        out[b * 6 + t] = a;
    }
}

// ---------------------------------------------------------------------------
extern "C" void kernel_launch(void* const* d_in, const int* in_sizes, int n_in,
                              void* d_out, int out_size, void* d_ws, size_t ws_size,
                              hipStream_t stream) {
    const float* nodes   = (const float*)d_in[0];
    const float* pos     = (const float*)d_in[1];
    const float* attmap  = (const float*)d_in[2];
    // d_in[3] = depths : unused by the reference
    const float* conv1_w = (const float*)d_in[4];
    const float* conv1_b = (const float*)d_in[5];
    const float* conv2_w = (const float*)d_in[6];
    const float* conv2_b = (const float*)d_in[7];
    const float* lin_w   = (const float*)d_in[8];
    const float* lin_b   = (const float*)d_in[9];
    const float* wfc_w   = (const float*)d_in[10];
    const float* wfc_b   = (const float*)d_in[11];
    const float* fm_w    = (const float*)d_in[12];
    const float* fm_b    = (const float*)d_in[13];
    const float* lm_w    = (const float*)d_in[14];
    const float* lm_b    = (const float*)d_in[15];
    const float* fc1_w   = (const float*)d_in[16];
    const float* fc1_b   = (const float*)d_in[17];
    const float* fc2_w   = (const float*)d_in[18];
    const float* fc2_b   = (const float*)d_in[19];
    const float* fc3_w   = (const float*)d_in[20];
    const float* fc3_b   = (const float*)d_in[21];

    float* h1      = (float*)d_ws;                         // 320 * 4108 floats
    float* feat_ws = h1 + (size_t)NIMG * H1_IMG;           // 320*6 floats

    k1_conv1_pool<<<NIMG * H1_HW, 256, 0, stream>>>(nodes, conv1_w, conv1_b, h1);
    k2_conv2_pool_lin<<<NIMG, 128, 0, stream>>>(h1, conv2_w, conv2_b, lin_w, lin_b, feat_ws);
    k3_graph_mlp<<<NB, 128, 0, stream>>>(feat_ws, pos, attmap,
                                         wfc_w, wfc_b, fm_w, fm_b, lm_w, lm_b,
                                         fc1_w, fc1_b, fc2_w, fc2_b, fc3_w, fc3_b,
                                         (float*)d_out);
}